// Round 1
// baseline (14001.276 us; speedup 1.0000x reference)
//
#include <hip/hip_runtime.h>
#include <math.h>

// Problem constants (from reference): B=128, L=512, D_IN=512, D_H=1024, D_OUT=256
#define B_   128
#define L_   512
#define DIN  512
#define DH   1024
#define DOUT 256

// ---------------------------------------------------------------------------
// proj_gemm: Z[(t-t0)*B + b][j] = sum_k X[b][t][k]*W[j][k] + bias[j]
// Tile 64x64, BK=16, 256 threads, 4x4 micro-tile, transposed LDS (As[k][m]).
// ---------------------------------------------------------------------------
__global__ __launch_bounds__(256) void proj_gemm(
    const float* __restrict__ X, const float* __restrict__ W,
    const float* __restrict__ bias, float* __restrict__ Z,
    int t0, int rows) {
  __shared__ __align__(16) float As[16][68];
  __shared__ __align__(16) float Bs[16][68];
  const int n0 = blockIdx.x * 64;
  const int m0 = blockIdx.y * 64;
  const int tid = (int)threadIdx.x;
  const int tx = tid & 15, ty = tid >> 4;
  const int lm = tid >> 2;        // 0..63 : tile row
  const int lk = (tid & 3) << 2;  // 0,4,8,12 : k offset
  const int r = m0 + lm;          // chunk row index (t-major)
  const int t = t0 + r / B_;
  const int b = r & (B_ - 1);
  const float* arow = X + ((size_t)b * L_ + t) * DIN + lk;
  const float* brow = W + (size_t)(n0 + lm) * DIN + lk;
  float acc[4][4] = {};
  for (int k0 = 0; k0 < DIN; k0 += 16) {
    const float4 av = *(const float4*)(arow + k0);
    const float4 bv = *(const float4*)(brow + k0);
    __syncthreads();
    As[lk + 0][lm] = av.x; As[lk + 1][lm] = av.y;
    As[lk + 2][lm] = av.z; As[lk + 3][lm] = av.w;
    Bs[lk + 0][lm] = bv.x; Bs[lk + 1][lm] = bv.y;
    Bs[lk + 2][lm] = bv.z; Bs[lk + 3][lm] = bv.w;
    __syncthreads();
#pragma unroll
    for (int kk = 0; kk < 16; ++kk) {
      const float4 a4 = *(const float4*)&As[kk][ty << 2];
      const float4 b4 = *(const float4*)&Bs[kk][tx << 2];
      const float a_[4] = {a4.x, a4.y, a4.z, a4.w};
      const float b_[4] = {b4.x, b4.y, b4.z, b4.w};
#pragma unroll
      for (int i = 0; i < 4; ++i)
#pragma unroll
        for (int j = 0; j < 4; ++j) acc[i][j] += a_[i] * b_[j];
    }
  }
  const int nc = n0 + (tx << 2);
  const float b0 = bias[nc + 0], b1 = bias[nc + 1], b2 = bias[nc + 2], b3 = bias[nc + 3];
#pragma unroll
  for (int i = 0; i < 4; ++i) {
    float4 v;
    v.x = acc[i][0] + b0; v.y = acc[i][1] + b1;
    v.z = acc[i][2] + b2; v.w = acc[i][3] + b3;
    *(float4*)&Z[(size_t)(m0 + (ty << 2) + i) * DH + nc] = v;
  }
}

// ---------------------------------------------------------------------------
// rec_gemm: Cout[m][n] = tanh( A[m][:]·W[n][:] + addend[m][n]? + bias[n]? )
// A is M=128 x K=1024 (h), W is N x 1024. Tile 16x32, BK=32, 128 threads,
// 2x2 micro-tile, transposed LDS. Used for the recurrent step (addend = Z_t)
// and for the output layer (bias = b_out, N=256).
// ---------------------------------------------------------------------------
__global__ __launch_bounds__(128) void rec_gemm(
    const float* __restrict__ A, const float* __restrict__ W,
    const float* __restrict__ addend, const float* __restrict__ bias,
    float* __restrict__ Cout, int N) {
  __shared__ __align__(16) float As[32][18];
  __shared__ __align__(16) float Bs[32][34];
  const int n0 = blockIdx.x * 32;
  const int m0 = blockIdx.y * 16;
  const int tid = (int)threadIdx.x;
  const int tx = tid & 15, ty = tid >> 4;  // tx:0..15 (n), ty:0..7 (m)
  const int am = tid >> 3;                 // 0..15
  const int ak = (tid & 7) << 2;           // 0..28
  const float* arow  = A + (size_t)(m0 + am) * DH + ak;
  const float* wrow0 = W + (size_t)(n0 + am) * DH + ak;
  const float* wrow1 = W + (size_t)(n0 + am + 16) * DH + ak;
  float acc[2][2] = {};
  for (int k0 = 0; k0 < DH; k0 += 32) {
    const float4 av  = *(const float4*)(arow + k0);
    const float4 bv0 = *(const float4*)(wrow0 + k0);
    const float4 bv1 = *(const float4*)(wrow1 + k0);
    __syncthreads();
    As[ak + 0][am] = av.x;  As[ak + 1][am] = av.y;
    As[ak + 2][am] = av.z;  As[ak + 3][am] = av.w;
    Bs[ak + 0][am] = bv0.x; Bs[ak + 1][am] = bv0.y;
    Bs[ak + 2][am] = bv0.z; Bs[ak + 3][am] = bv0.w;
    Bs[ak + 0][am + 16] = bv1.x; Bs[ak + 1][am + 16] = bv1.y;
    Bs[ak + 2][am + 16] = bv1.z; Bs[ak + 3][am + 16] = bv1.w;
    __syncthreads();
#pragma unroll
    for (int kk = 0; kk < 32; ++kk) {
      const float2 a2 = *(const float2*)&As[kk][ty << 1];
      const float2 b2 = *(const float2*)&Bs[kk][tx << 1];
      acc[0][0] += a2.x * b2.x; acc[0][1] += a2.x * b2.y;
      acc[1][0] += a2.y * b2.x; acc[1][1] += a2.y * b2.y;
    }
  }
  const int m = m0 + (ty << 1);
  const int n = n0 + (tx << 1);
#pragma unroll
  for (int i = 0; i < 2; ++i)
#pragma unroll
    for (int j = 0; j < 2; ++j) {
      float v = acc[i][j];
      if (addend) v += addend[(size_t)(m + i) * N + (n + j)];
      if (bias) v += bias[n + j];
      Cout[(size_t)(m + i) * N + (n + j)] = tanhf(v);
    }
}

// h = tanh(Z[1])  (steps l<2 have rec zeroed, so l=1 is a pure elementwise tanh)
__global__ __launch_bounds__(256) void tanh_ew(const float* __restrict__ in,
                                               float* __restrict__ out, int n) {
  const int i = blockIdx.x * 256 + (int)threadIdx.x;
  if (i < n) out[i] = tanhf(in[i]);
}

extern "C" void kernel_launch(void* const* d_in, const int* in_sizes, int n_in,
                              void* d_out, int out_size, void* d_ws, size_t ws_size,
                              hipStream_t stream) {
  const float* X      = (const float*)d_in[0];
  const float* W_in1  = (const float*)d_in[1];
  const float* b_in1  = (const float*)d_in[2];
  const float* W_rec1 = (const float*)d_in[3];
  // d_in[4..6] = W_in2/b_in2/W_rec2 : dead code w.r.t. Y
  const float* W_out  = (const float*)d_in[7];
  const float* b_out  = (const float*)d_in[8];
  float* out = (float*)d_out;

  // Workspace layout: [ Z chunk: C*B*DH floats | hA: B*DH | hB: B*DH ]
  const size_t stepZf = (size_t)B_ * DH;  // floats per timestep slot (512 KB)
  const size_t capf = ws_size / sizeof(float);
  long maxC = (long)(capf / stepZf) - 2;
  int C = (int)(maxC < 1 ? 1 : (maxC > (L_ - 1) ? (L_ - 1) : maxC));

  float* Zc = (float*)d_ws;
  float* hA = Zc + (size_t)C * stepZf;
  float* hB = hA + stepZf;
  float* hprev = nullptr;

  int t = 1;  // step l=0 never influences the output
  while (t < L_) {
    int te = t + C; if (te > L_) te = L_;
    const int rows = (te - t) * B_;  // multiple of 64
    proj_gemm<<<dim3(DH / 64, rows / 64), 256, 0, stream>>>(X, W_in1, b_in1, Zc, t, rows);
    for (int l = t; l < te; ++l) {
      const float* zrow = Zc + (size_t)(l - t) * stepZf;
      if (l == 1) {
        tanh_ew<<<(B_ * DH) / 256, 256, 0, stream>>>(zrow, hA, B_ * DH);
        hprev = hA;
      } else {
        float* hn = (hprev == hA) ? hB : hA;
        rec_gemm<<<dim3(DH / 32, B_ / 16), 128, 0, stream>>>(
            hprev, W_rec1, zrow, nullptr, hn, DH);
        hprev = hn;
      }
    }
    t = te;
  }
  // Y = tanh(hL @ W_out^T + b_out)
  rec_gemm<<<dim3(DOUT / 32, B_ / 16), 128, 0, stream>>>(
      hprev, W_out, nullptr, b_out, out, DOUT);
}